// Round 11
// baseline (1381.861 us; speedup 1.0000x reference)
//
#include <hip/hip_runtime.h>
#include <math.h>

#define Nn 16384
#define Fd 64
#define Hd 128
#define Kk 32

typedef short bfrag __attribute__((ext_vector_type(8)));    // 8 bf16 = 4 VGPR
typedef float f32x16 __attribute__((ext_vector_type(16)));  // MFMA 32x32 acc

#define FMA16(acc, qv, pv) \
  acc[0][0]=fmaf(qv.x,pv.x,acc[0][0]); acc[0][1]=fmaf(qv.x,pv.y,acc[0][1]); \
  acc[0][2]=fmaf(qv.x,pv.z,acc[0][2]); acc[0][3]=fmaf(qv.x,pv.w,acc[0][3]); \
  acc[1][0]=fmaf(qv.y,pv.x,acc[1][0]); acc[1][1]=fmaf(qv.y,pv.y,acc[1][1]); \
  acc[1][2]=fmaf(qv.y,pv.z,acc[1][2]); acc[1][3]=fmaf(qv.y,pv.w,acc[1][3]); \
  acc[2][0]=fmaf(qv.z,pv.x,acc[2][0]); acc[2][1]=fmaf(qv.z,pv.y,acc[2][1]); \
  acc[2][2]=fmaf(qv.z,pv.z,acc[2][2]); acc[2][3]=fmaf(qv.z,pv.w,acc[2][3]); \
  acc[3][0]=fmaf(qv.w,pv.x,acc[3][0]); acc[3][1]=fmaf(qv.w,pv.y,acc[3][1]); \
  acc[3][2]=fmaf(qv.w,pv.z,acc[3][2]); acc[3][3]=fmaf(qv.w,pv.w,acc[3][3]);

// ---------------- hidden0 = x @ W_in + b_in ; sq[i] = sum(x_i^2) ----------------
__global__ __launch_bounds__(256) void k_input(const float* __restrict__ x,
    const float* __restrict__ W, const float* __restrict__ b,
    float* __restrict__ hid, float* __restrict__ sq) {
  const int t = threadIdx.x;
  const int i = (blockIdx.x << 1) + (t >> 7);
  const int h = t & 127;
  const float* xr = x + (size_t)i * Fd;
  float acc = 0.f, s = 0.f;
#pragma unroll 8
  for (int f = 0; f < Fd; ++f) {
    float xv = xr[f];
    acc = fmaf(xv, W[f * Hd + h], acc);
    s = fmaf(xv, xv, s);
  }
  hid[(size_t)i * Hd + h] = acc + b[h];
  if (h == 0) sq[i] = s;
}

// ------------- precompute x as bf16 hi/lo in MFMA-fragment order -------------
__global__ __launch_bounds__(256) void k_prep(const float* __restrict__ x,
    short* __restrict__ xh, short* __restrict__ xl) {
  const int gid = blockIdx.x * 256 + threadIdx.x;
  const int p = gid >> 3, sub = gid & 7;
  const float* src = x + (size_t)p * Fd + sub * 8;
  float4 v0 = *(const float4*)src;
  float4 v1 = *(const float4*)(src + 4);
  float vv[8] = {v0.x, v0.y, v0.z, v0.w, v1.x, v1.y, v1.z, v1.w};
  bfrag hi, lo;
#pragma unroll
  for (int j = 0; j < 8; ++j) {
    unsigned u = __float_as_uint(vv[j]);
    unsigned r = u + 0x7fffu + ((u >> 16) & 1u);
    unsigned short hb = (unsigned short)(r >> 16);
    float hf = __uint_as_float((unsigned)hb << 16);
    float lof = vv[j] - hf;
    unsigned ul = __float_as_uint(lof);
    unsigned rl = ul + 0x7fffu + ((ul >> 16) & 1u);
    hi[j] = (short)hb;
    lo[j] = (short)(rl >> 16);
  }
  const size_t o = (size_t)(p >> 5) * 2048 + (size_t)sub * 256 + (size_t)(p & 31) * 8;
  *(bfrag*)(xh + o) = hi;
  *(bfrag*)(xl + o) = lo;
}

// ---------------- KNN pass 1: split-K, lane-private top-32, float-first filter ----------------
// Grid 1024: (qblk = bid>>1, half = bid&1), 64 tiles of 128 pts each.
// mfma(A=points, B=queries): lane (q=lane&31, h=lane>>5) holds 16 pt-dists of ITS
// query in regs. Per-lane top-32 u32 keys (dq18<<14|pidx) in LDS; bootstrap fills
// all 32 slots (no cnt branch); steady filter = float cmp, static unroll; insert =
// one fused max+2ndmax rescan. Deterministic (exact keys, fixed order).
#define LSTR 33

__global__ __launch_bounds__(256, 3) void k_knn(const short* __restrict__ xbhi,
    const short* __restrict__ xblo, const float* __restrict__ sq,
    unsigned* __restrict__ part) {
  __shared__ unsigned tk[256 * LSTR];   // lane-private lists (33.8 KB)
  __shared__ unsigned ms[512];          // merge scratch (2 KB)

  const int t = threadIdx.x;
  const int w = t >> 6;
  const int lane = t & 63;
  const int h = lane >> 5;
  const int q = lane & 31;
  const int qblk = (int)(blockIdx.x >> 1);
  const int half = (int)(blockIdx.x & 1);
  const int qg0 = qblk * 32;
  const int t0 = half * 64;
  const int selfq = qg0 + q;
  const float sqq = sq[selfq];
  const int selfTl = qg0 >> 7;            // wave-uniform
  const int selfW = (qg0 >> 5) & 3;       // wave-uniform
  const int selfH = (q >> 2) & 1;
  const int selfR = (q & 3) + 4 * (q >> 3);

  const char* xh = (const char*)xbhi;
  const char* xl = (const char*)xblo;

  bfrag qhi[4], qlo[4];
  {
    const size_t a0 = (size_t)qblk * 4096 + (size_t)lane * 16;
#pragma unroll
    for (int s = 0; s < 4; ++s) {
      qhi[s] = *(const bfrag*)(xh + a0 + s * 1024);
      qlo[s] = *(const bfrag*)(xl + a0 + s * 1024);
    }
  }
  asm volatile("" :: "v"(qhi[0]), "v"(qhi[1]), "v"(qhi[2]), "v"(qhi[3]),
                     "v"(qlo[0]), "v"(qlo[1]), "v"(qlo[2]), "v"(qlo[3]));

  unsigned* mylist = &tk[t * LSTR];
  float thrF = 1e38f;

#define LOADP(GT, PH, PL) { \
  const size_t bb_ = (size_t)((GT) * 4 + w) * 4096 + (size_t)lane * 16; \
  _Pragma("unroll") for (int s_ = 0; s_ < 4; ++s_) { \
    PH[s_] = *(const bfrag*)(xh + bb_ + s_ * 1024); \
    PL[s_] = *(const bfrag*)(xl + bb_ + s_ * 1024); } }

#define SQLOAD(GT, SQv) { \
  const float* sb_ = sq + (GT) * 128 + w * 32 + 4 * h; \
  const float4 q0_ = *(const float4*)(sb_); \
  const float4 q1_ = *(const float4*)(sb_ + 8); \
  const float4 q2_ = *(const float4*)(sb_ + 16); \
  const float4 q3_ = *(const float4*)(sb_ + 24); \
  SQv[0]=q0_.x; SQv[1]=q0_.y; SQv[2]=q0_.z; SQv[3]=q0_.w; \
  SQv[4]=q1_.x; SQv[5]=q1_.y; SQv[6]=q1_.z; SQv[7]=q1_.w; \
  SQv[8]=q2_.x; SQv[9]=q2_.y; SQv[10]=q2_.z; SQv[11]=q2_.w; \
  SQv[12]=q3_.x; SQv[13]=q3_.y; SQv[14]=q3_.z; SQv[15]=q3_.w; }

#define PIN(PH, PL) asm volatile("" :: "v"(PH[0]), "v"(PH[1]), "v"(PH[2]), "v"(PH[3]), \
                                       "v"(PL[0]), "v"(PL[1]), "v"(PL[2]), "v"(PL[3]));

#define MFMA12(A0, PH, PL) { \
  _Pragma("unroll") for (int s_ = 0; s_ < 4; ++s_) \
    A0 = __builtin_amdgcn_mfma_f32_32x32x16_bf16(PH[s_], qhi[s_], A0, 0, 0, 0); \
  _Pragma("unroll") for (int s_ = 0; s_ < 4; ++s_) \
    A0 = __builtin_amdgcn_mfma_f32_32x32x16_bf16(PH[s_], qlo[s_], A0, 0, 0, 0); \
  _Pragma("unroll") for (int s_ = 0; s_ < 4; ++s_) \
    A0 = __builtin_amdgcn_mfma_f32_32x32x16_bf16(PL[s_], qhi[s_], A0, 0, 0, 0); }

  // in-place: a0[r] = d2 = sqq + sqp - 2*dot ; self nullified (one tile, uniform branch)
#define DCALC(A0, SQv, GT) { \
  _Pragma("unroll") for (int r_ = 0; r_ < 16; ++r_) \
    A0[r_] = fmaf(-2.0f, A0[r_], sqq + SQv[r_]); \
  if ((GT) == selfTl && w == selfW) { \
    _Pragma("unroll") for (int r_ = 0; r_ < 16; ++r_) \
      if (h == selfH && r_ == selfR) A0[r_] = 1e30f; } }

#define PACKKEY(D2, PIDX, KEY) { \
  unsigned dq_ = (unsigned)((D2) * 256.0f); \
  dq_ = dq_ > 0x3FFEFu ? 0x3FFEFu : dq_; \
  KEY = (dq_ << 14) | (unsigned)(PIDX); }

#define FILTINS(A0, GT) { \
  const int pb_ = (GT) * 128 + w * 32 + 4 * h; \
  _Pragma("unroll") for (int r_ = 0; r_ < 16; ++r_) { \
    if (A0[r_] < thrF) { \
      unsigned key_; PACKKEY(A0[r_], pb_ + r_ + (r_ & ~3), key_) \
      unsigned mx_ = 0u, mx2_ = 0u; int mp_ = 0; \
      _Pragma("unroll") for (int e_ = 0; e_ < 32; ++e_) { \
        const unsigned v_ = mylist[e_]; \
        if (v_ > mx_) { mx2_ = mx_; mx_ = v_; mp_ = e_; } \
        else if (v_ > mx2_) mx2_ = v_; } \
      if (key_ < mx_) { \
        mylist[mp_] = key_; \
        const unsigned nt_ = mx2_ > key_ ? mx2_ : key_; \
        thrF = (float)((nt_ >> 14) + 1) * (1.0f / 256.0f); \
      } else { \
        thrF = (float)((mx_ >> 14) + 1) * (1.0f / 256.0f); \
      } } } }

#define STEP(LT, PHc, PLc, SQc, PHn, PLn, SQn) { \
  const int gT_ = t0 + (LT); \
  if ((LT) + 1 < 64) { LOADP(gT_ + 1, PHn, PLn) SQLOAD(gT_ + 1, SQn) } \
  f32x16 a0_; \
  _Pragma("unroll") for (int i_ = 0; i_ < 16; ++i_) a0_[i_] = 0.f; \
  MFMA12(a0_, PHc, PLc) \
  PIN(PHn, PLn) \
  DCALC(a0_, SQc, gT_) \
  FILTINS(a0_, gT_) }

  bfrag phA[4], plA[4], phB[4], plB[4];
  float sA[16], sB[16];

  // ---- bootstrap: tiles t0, t0+1 fill all 32 slots (no compares) ----
  LOADP(t0, phA, plA) SQLOAD(t0, sA)
  {
    f32x16 a0_;
#pragma unroll
    for (int i_ = 0; i_ < 16; ++i_) a0_[i_] = 0.f;
    MFMA12(a0_, phA, plA)
    LOADP(t0 + 1, phB, plB) SQLOAD(t0 + 1, sB) PIN(phB, plB)
    DCALC(a0_, sA, t0)
    const int pb0 = t0 * 128 + w * 32 + 4 * h;
#pragma unroll
    for (int r_ = 0; r_ < 16; ++r_) {
      unsigned key_; PACKKEY(a0_[r_], pb0 + r_ + (r_ & ~3), key_)
      mylist[r_] = key_;
    }
  }
  {
    f32x16 a0_;
#pragma unroll
    for (int i_ = 0; i_ < 16; ++i_) a0_[i_] = 0.f;
    MFMA12(a0_, phB, plB)
    LOADP(t0 + 2, phA, plA) SQLOAD(t0 + 2, sA) PIN(phA, plA)
    DCALC(a0_, sB, t0 + 1)
    const int pb1 = (t0 + 1) * 128 + w * 32 + 4 * h;
#pragma unroll
    for (int r_ = 0; r_ < 16; ++r_) {
      unsigned key_; PACKKEY(a0_[r_], pb1 + r_ + (r_ & ~3), key_)
      mylist[16 + r_] = key_;
    }
    unsigned mx_ = 0u;
#pragma unroll
    for (int e_ = 0; e_ < 32; ++e_) {
      const unsigned v_ = mylist[e_];
      mx_ = v_ > mx_ ? v_ : mx_;
    }
    thrF = (float)((mx_ >> 14) + 1) * (1.0f / 256.0f);
  }

  // ---- steady tiles 2..63 ----
  for (int lt = 2; lt < 62; lt += 2) {
    STEP(lt, phA, plA, sA, phB, plB, sB)
    STEP(lt + 1, phB, plB, sB, phA, plA, sA)
  }
  STEP(62, phA, plA, sA, phB, plB, sB)
  STEP(63, phB, plB, sB, phA, plA, sA)

  __syncthreads();

  // ---- in-block merge: 8 lane-lists -> sorted top-32/query -> part ----
#define SORT64(V) { \
  _Pragma("unroll") for (int k_ = 2; k_ <= 64; k_ <<= 1) { \
    _Pragma("unroll") for (int j_ = k_ >> 1; j_ >= 1; j_ >>= 1) { \
      const unsigned o_ = (unsigned)__shfl_xor((int)V, j_); \
      const bool km_ = ((lane & j_) == 0) == ((lane & k_) == 0); \
      V = km_ ? (V < o_ ? V : o_) : (V > o_ ? V : o_); \
    } } }

#define MERGE6(V) { \
  _Pragma("unroll") for (int j_ = 32; j_ >= 1; j_ >>= 1) { \
    const unsigned o_ = (unsigned)__shfl_xor((int)V, j_); \
    const bool km_ = ((lane & j_) == 0); \
    V = km_ ? (V < o_ ? V : o_) : (V > o_ ? V : o_); \
  } }

  unsigned* S = &ms[w * 128];
  for (int s8 = 0; s8 < 8; ++s8) {
    const int qq = w * 8 + s8;
#pragma unroll
    for (int w2 = 0; w2 < 4; ++w2) {
      unsigned v = tk[(w2 * 64 + (lane & 32) + qq) * LSTR + (lane & 31)];
      SORT64(v)
      if (lane < 32) S[w2 * 32 + lane] = v;
    }
    {
      unsigned v = (lane < 32) ? S[0 * 32 + lane] : S[1 * 32 + (63 - lane)];
      MERGE6(v)
      if (lane < 32) S[0 * 32 + lane] = v;
    }
    {
      unsigned v = (lane < 32) ? S[2 * 32 + lane] : S[3 * 32 + (63 - lane)];
      MERGE6(v)
      if (lane < 32) S[2 * 32 + lane] = v;
    }
    {
      unsigned v = (lane < 32) ? S[0 * 32 + lane] : S[2 * 32 + (63 - lane)];
      MERGE6(v)
      if (lane < 32)
        part[(size_t)(qg0 + qq) * 64 + half * 32 + lane] = v;
    }
  }
#undef LOADP
#undef SQLOAD
#undef PIN
#undef MFMA12
#undef DCALC
#undef PACKKEY
#undef FILTINS
#undef STEP
#undef SORT64
#undef MERGE6
}

// ---------------- KNN pass 2: merge two sorted-32 lists + softmax ----------------
__global__ __launch_bounds__(256) void k_merge(const unsigned* __restrict__ part,
    unsigned short* __restrict__ nidx, float* __restrict__ nw) {
  const int t = threadIdx.x;
  const int w = t >> 6;
  const int lane = t & 63;
  const int q = (int)blockIdx.x * 4 + w;
  const int src = (lane < 32) ? lane : (95 - lane);
  unsigned v = part[(size_t)q * 64 + src];
#pragma unroll
  for (int j = 32; j >= 1; j >>= 1) {
    const unsigned o = (unsigned)__shfl_xor((int)v, j);
    const bool mn = ((lane & j) == 0);
    v = mn ? (v < o ? v : o) : (v > o ? v : o);
  }
  const float d = sqrtf((float)(v >> 14) * (1.0f / 256.0f));
  const float dmin = __shfl(d, 0);
  float e = (lane < 32) ? __expf((dmin - d) * 2.0f) : 0.f;
  float s2 = e;
#pragma unroll
  for (int m = 1; m < 64; m <<= 1) s2 += __shfl_xor(s2, m);
  if (lane < 32) {
    nw[(size_t)q * Kk + lane] = e / s2;
    nidx[(size_t)q * Kk + lane] = (unsigned short)(v & 0x3FFFu);
  }
}

// ---------------- one message-pass step, fused: gather+MLP+LN ----------------
#define RB 32
#define US 36

__global__ __launch_bounds__(256) void k_step(const float* __restrict__ x,
    const float* __restrict__ hin, const unsigned short* __restrict__ nidx,
    const float* __restrict__ nw, const float* __restrict__ Wm1,
    const float* __restrict__ bm1, const float* __restrict__ Wm2,
    const float* __restrict__ bm2, const float* __restrict__ g,
    const float* __restrict__ be, float* __restrict__ hout) {
  __shared__ float updT[2 * Hd + Fd][US];  // upd_in transposed: 320 x 36 (46 KB)
  __shared__ float t1T[Hd][US];            // silu(GEMM1) transposed (18 KB)
  const int t = threadIdx.x;
  const int r0 = blockIdx.x * RB;

  { // stage: hidden | agg (gather) | x, all transposed
    const int r = t >> 3, s = t & 7;
    const int i = r0 + r;
    const float* hr = hin + (size_t)i * Hd + (s << 4);
#pragma unroll
    for (int u = 0; u < 4; ++u) {
      float4 v = *(const float4*)(hr + (u << 2));
      const int c = (s << 4) + (u << 2);
      updT[c + 0][r] = v.x; updT[c + 1][r] = v.y;
      updT[c + 2][r] = v.z; updT[c + 3][r] = v.w;
    }
    float a[16];
#pragma unroll
    for (int u = 0; u < 16; ++u) a[u] = 0.f;
    const unsigned short* ir = nidx + i * Kk;
    const float* wr = nw + i * Kk;
    for (int k = 0; k < Kk; ++k) {
      const float wk = wr[k];
      const float* hv = hin + (size_t)ir[k] * Hd + (s << 4);
#pragma unroll
      for (int u = 0; u < 4; ++u) {
        float4 v = *(const float4*)(hv + (u << 2));
        a[(u << 2) + 0] = fmaf(wk, v.x, a[(u << 2) + 0]);
        a[(u << 2) + 1] = fmaf(wk, v.y, a[(u << 2) + 1]);
        a[(u << 2) + 2] = fmaf(wk, v.z, a[(u << 2) + 2]);
        a[(u << 2) + 3] = fmaf(wk, v.w, a[(u << 2) + 3]);
      }
    }
#pragma unroll
    for (int u = 0; u < 16; ++u) updT[Hd + (s << 4) + u][r] = a[u];
    const float* xr = x + (size_t)i * Fd + (s << 3);
    float4 x0 = *(const float4*)(xr);
    float4 x1 = *(const float4*)(xr + 4);
    const int c = 2 * Hd + (s << 3);
    updT[c + 0][r] = x0.x; updT[c + 1][r] = x0.y;
    updT[c + 2][r] = x0.z; updT[c + 3][r] = x0.w;
    updT[c + 4][r] = x1.x; updT[c + 5][r] = x1.y;
    updT[c + 6][r] = x1.z; updT[c + 7][r] = x1.w;
  }
  __syncthreads();

  const int rg = t >> 5, cg = t & 31;
  const int rr = rg << 2, cc = cg << 2;
  { // GEMM1 [32x320]x[320x128] + silu -> t1T
    float acc[4][4] = {};
#pragma unroll 4
    for (int k = 0; k < 2 * Hd + Fd; ++k) {
      float4 uv = *(const float4*)&updT[k][rr];
      float4 wv = *(const float4*)&Wm1[k * Hd + cc];
      FMA16(acc, uv, wv)
    }
    float4 b1 = *(const float4*)&bm1[cc];
    float bb1[4] = {b1.x, b1.y, b1.z, b1.w};
#pragma unroll
    for (int a = 0; a < 4; ++a)
#pragma unroll
      for (int b = 0; b < 4; ++b) {
        const float z = acc[a][b] + bb1[b];
        t1T[cc + b][rr + a] = z / (1.0f + __expf(-z));
      }
  }
  __syncthreads();
  { // GEMM2 [32x128]x[128x128] + residual + LayerNorm
    float acc[4][4] = {};
#pragma unroll 4
    for (int k = 0; k < Hd; ++k) {
      float4 uv = *(const float4*)&t1T[k][rr];
      float4 wv = *(const float4*)&Wm2[k * Hd + cc];
      FMA16(acc, uv, wv)
    }
    float4 b2 = *(const float4*)&bm2[cc];
    float bb2[4] = {b2.x, b2.y, b2.z, b2.w};
    float v[4][4];
#pragma unroll
    for (int b = 0; b < 4; ++b) {
      float4 hres = *(const float4*)&updT[cc + b][rr];  // residual = staged hidden
      v[0][b] = hres.x + acc[0][b] + bb2[b];
      v[1][b] = hres.y + acc[1][b] + bb2[b];
      v[2][b] = hres.z + acc[2][b] + bb2[b];
      v[3][b] = hres.w + acc[3][b] + bb2[b];
    }
    float4 gv = *(const float4*)&g[cc];
    float4 bev = *(const float4*)&be[cc];
    float gg[4] = {gv.x, gv.y, gv.z, gv.w};
    float eb[4] = {bev.x, bev.y, bev.z, bev.w};
#pragma unroll
    for (int a = 0; a < 4; ++a) {
      float sm = v[a][0] + v[a][1] + v[a][2] + v[a][3];
      float s2 = 0.f;
#pragma unroll
      for (int b = 0; b < 4; ++b) s2 = fmaf(v[a][b], v[a][b], s2);
#pragma unroll
      for (int m = 1; m < 32; m <<= 1) {
        sm += __shfl_xor(sm, m);
        s2 += __shfl_xor(s2, m);
      }
      const float mean = sm * (1.0f / 128.0f);
      const float var = fmaxf(s2 * (1.0f / 128.0f) - mean * mean, 0.0f);
      const float rstd = rsqrtf(var + 1e-5f);
      float4 o;
      o.x = (v[a][0] - mean) * rstd * gg[0] + eb[0];
      o.y = (v[a][1] - mean) * rstd * gg[1] + eb[1];
      o.z = (v[a][2] - mean) * rstd * gg[2] + eb[2];
      o.w = (v[a][3] - mean) * rstd * gg[3] + eb[3];
      *(float4*)&hout[(size_t)(r0 + rr + a) * Hd + cc] = o;
    }
  }
}

// ---------------- readout: softplus(silu([h,x]@Wr1+b)@Wr2+b) ----------------
__global__ __launch_bounds__(256) void k_out(const float* __restrict__ x,
    const float* __restrict__ hin, const float* __restrict__ Wr1,
    const float* __restrict__ br1, const float* __restrict__ Wr2,
    const float* __restrict__ br2, float* __restrict__ out) {
  __shared__ float rT[Hd + Fd][US];  // 192 x 36 (27 KB)
  const int t = threadIdx.x;
  const int r0 = blockIdx.x * RB;
  {
    const int r = t >> 3, s = t & 7;
    const int i = r0 + r;
    const float* hr = hin + (size_t)i * Hd + (s << 4);
#pragma unroll
    for (int u = 0; u < 4; ++u) {
      float4 v = *(const float4*)(hr + (u << 2));
      const int c = (s << 4) + (u << 2);
      rT[c + 0][r] = v.x; rT[c + 1][r] = v.y;
      rT[c + 2][r] = v.z; rT[c + 3][r] = v.w;
    }
    const float* xr = x + (size_t)i * Fd + (s << 3);
    float4 x0 = *(const float4*)(xr);
    float4 x1 = *(const float4*)(xr + 4);
    const int c = Hd + (s << 3);
    rT[c + 0][r] = x0.x; rT[c + 1][r] = x0.y;
    rT[c + 2][r] = x0.z; rT[c + 3][r] = x0.w;
    rT[c + 4][r] = x1.x; rT[c + 5][r] = x1.y;
    rT[c + 6][r] = x1.z; rT[c + 7][r] = x1.w;
  }
  __syncthreads();
  const int rg = t >> 5, cg = t & 31;
  const int rr = rg << 2, cc = cg << 2;
  float acc[4][4] = {};
#pragma unroll 4
  for (int k = 0; k < Hd + Fd; ++k) {
    float4 uv = *(const float4*)&rT[k][rr];
    float4 wv = *(const float4*)&Wr1[k * Hd + cc];
    FMA16(acc, uv, wv)
  }
  float4 b1 = *(const float4*)&br1[cc];
  float bb1[4] = {b1.x, b1.y, b1.z, b1.w};
  float4 w2 = *(const float4*)&Wr2[cc];
  float ww[4] = {w2.x, w2.y, w2.z, w2.w};
  float part[4];
#pragma unroll
  for (int a = 0; a < 4; ++a) {
    part[a] = 0.f;
#pragma unroll
    for (int b = 0; b < 4; ++b) {
      const float z = acc[a][b] + bb1[b];
      const float sil = z / (1.0f + __expf(-z));
      part[a] = fmaf(sil, ww[b], part[a]);
    }
  }
#pragma unroll
  for (int m = 1; m < 32; m <<= 1) {
#pragma unroll
    for (int a = 0; a < 4; ++a) part[a] += __shfl_xor(part[a], m);
  }
  if (cg == 0) {
    const float bias = br2[0];
#pragma unroll
    for (int a = 0; a < 4; ++a) {
      const float rv = part[a] + bias;
      out[r0 + rr + a] = fmaxf(rv, 0.0f) + log1pf(__expf(-fabsf(rv)));
    }
  }
}

extern "C" void kernel_launch(void* const* d_in, const int* in_sizes, int n_in,
                              void* d_out, int out_size, void* d_ws, size_t ws_size,
                              hipStream_t stream) {
  const float* x    = (const float*)d_in[0];
  const float* W_in = (const float*)d_in[1];
  const float* b_in = (const float*)d_in[2];
  const float* W_m1 = (const float*)d_in[3];
  const float* b_m1 = (const float*)d_in[4];
  const float* W_m2 = (const float*)d_in[5];
  const float* b_m2 = (const float*)d_in[6];
  const float* ln_g = (const float*)d_in[7];
  const float* ln_b = (const float*)d_in[8];
  const float* W_r1 = (const float*)d_in[9];
  const float* b_r1 = (const float*)d_in[10];
  const float* W_r2 = (const float*)d_in[11];
  const float* b_r2 = (const float*)d_in[12];
  float* out = (float*)d_out;

  char* ws = (char*)d_ws;
  const size_t MB = (size_t)1 << 20;
  float*          hidA = (float*)(ws);                 // 8 MB
  float*          hidB = (float*)(ws + 8 * MB);        // 8 MB (aliases partbuf)
  unsigned*       partb = (unsigned*)(ws + 8 * MB);    // 4 MB, dead before hidB use
  short*          xbhi = (short*)(ws + 16 * MB);       // 2 MB
  short*          xblo = (short*)(ws + 18 * MB);       // 2 MB
  unsigned short* nidx = (unsigned short*)(ws + 20 * MB);  // 1 MB
  float*          nw   = (float*)(ws + 21 * MB);       // 2 MB
  float*          sq   = (float*)(ws + 23 * MB);       // 64 KB

  k_input<<<dim3(Nn / 2), dim3(256), 0, stream>>>(x, W_in, b_in, hidA, sq);
  k_prep<<<dim3(Nn * 8 / 256), dim3(256), 0, stream>>>(x, xbhi, xblo);
  k_knn<<<dim3(Nn / 32 * 2), dim3(256), 0, stream>>>(xbhi, xblo, sq, partb);
  k_merge<<<dim3(Nn / 4), dim3(256), 0, stream>>>(partb, nidx, nw);
  k_step<<<dim3(Nn / RB), dim3(256), 0, stream>>>(x, hidA, nidx, nw, W_m1, b_m1,
                                                  W_m2, b_m2, ln_g, ln_b, hidB);
  k_step<<<dim3(Nn / RB), dim3(256), 0, stream>>>(x, hidB, nidx, nw, W_m1, b_m1,
                                                  W_m2, b_m2, ln_g, ln_b, hidA);
  k_out<<<dim3(Nn / RB), dim3(256), 0, stream>>>(x, hidA, W_r1, b_r1, W_r2, b_r2, out);
}

// Round 12
// 666.855 us; speedup vs baseline: 2.0722x; 2.0722x over previous
//
#include <hip/hip_runtime.h>
#include <math.h>

#define Nn 16384
#define Fd 64
#define Hd 128
#define Kk 32

typedef short bfrag __attribute__((ext_vector_type(8)));    // 8 bf16 = 4 VGPR
typedef float f32x16 __attribute__((ext_vector_type(16)));  // MFMA 32x32 acc

#define FMA16(acc, qv, pv) \
  acc[0][0]=fmaf(qv.x,pv.x,acc[0][0]); acc[0][1]=fmaf(qv.x,pv.y,acc[0][1]); \
  acc[0][2]=fmaf(qv.x,pv.z,acc[0][2]); acc[0][3]=fmaf(qv.x,pv.w,acc[0][3]); \
  acc[1][0]=fmaf(qv.y,pv.x,acc[1][0]); acc[1][1]=fmaf(qv.y,pv.y,acc[1][1]); \
  acc[1][2]=fmaf(qv.y,pv.z,acc[1][2]); acc[1][3]=fmaf(qv.y,pv.w,acc[1][3]); \
  acc[2][0]=fmaf(qv.z,pv.x,acc[2][0]); acc[2][1]=fmaf(qv.z,pv.y,acc[2][1]); \
  acc[2][2]=fmaf(qv.z,pv.z,acc[2][2]); acc[2][3]=fmaf(qv.z,pv.w,acc[2][3]); \
  acc[3][0]=fmaf(qv.w,pv.x,acc[3][0]); acc[3][1]=fmaf(qv.w,pv.y,acc[3][1]); \
  acc[3][2]=fmaf(qv.w,pv.z,acc[3][2]); acc[3][3]=fmaf(qv.w,pv.w,acc[3][3]);

// ---------------- hidden0 = x @ W_in + b_in ; sq[i] = sum(x_i^2) ----------------
__global__ __launch_bounds__(256) void k_input(const float* __restrict__ x,
    const float* __restrict__ W, const float* __restrict__ b,
    float* __restrict__ hid, float* __restrict__ sq) {
  const int t = threadIdx.x;
  const int i = (blockIdx.x << 1) + (t >> 7);
  const int h = t & 127;
  const float* xr = x + (size_t)i * Fd;
  float acc = 0.f, s = 0.f;
#pragma unroll 8
  for (int f = 0; f < Fd; ++f) {
    float xv = xr[f];
    acc = fmaf(xv, W[f * Hd + h], acc);
    s = fmaf(xv, xv, s);
  }
  hid[(size_t)i * Hd + h] = acc + b[h];
  if (h == 0) sq[i] = s;
}

// ------------- precompute x as bf16 hi/lo in MFMA-fragment order -------------
__global__ __launch_bounds__(256) void k_prep(const float* __restrict__ x,
    short* __restrict__ xh, short* __restrict__ xl) {
  const int gid = blockIdx.x * 256 + threadIdx.x;
  const int p = gid >> 3, sub = gid & 7;
  const float* src = x + (size_t)p * Fd + sub * 8;
  float4 v0 = *(const float4*)src;
  float4 v1 = *(const float4*)(src + 4);
  float vv[8] = {v0.x, v0.y, v0.z, v0.w, v1.x, v1.y, v1.z, v1.w};
  bfrag hi, lo;
#pragma unroll
  for (int j = 0; j < 8; ++j) {
    unsigned u = __float_as_uint(vv[j]);
    unsigned r = u + 0x7fffu + ((u >> 16) & 1u);
    unsigned short hb = (unsigned short)(r >> 16);
    float hf = __uint_as_float((unsigned)hb << 16);
    float lof = vv[j] - hf;
    unsigned ul = __float_as_uint(lof);
    unsigned rl = ul + 0x7fffu + ((ul >> 16) & 1u);
    hi[j] = (short)hb;
    lo[j] = (short)(rl >> 16);
  }
  const size_t o = (size_t)(p >> 5) * 2048 + (size_t)sub * 256 + (size_t)(p & 31) * 8;
  *(bfrag*)(xh + o) = hi;
  *(bfrag*)(xl + o) = lo;
}

// ---------------- KNN pass 1: split-K, lane-private top-32, select-tree extract ----------------
// Grid 1024: (qblk = bid>>1, half = bid&1), 64 tiles of 128 pts each.
// mfma(A=points, B=queries): lane (q=lane&31, h=lane>>5) holds 16 pt-dists of ITS
// query in regs. Per-lane top-32 u32 keys (dq18<<14|pidx) in LDS (stride 33,
// conflict-free). Gate = cached max-key register; candidate extraction via a
// 15-cndmask select tree over the accumulator (no LDS staging). One fused
// rescan per actual insert. Deterministic (exact keys, fixed order).
#define LSTR 33

__global__ __launch_bounds__(256, 2) void k_knn(const short* __restrict__ xbhi,
    const short* __restrict__ xblo, const float* __restrict__ sq,
    unsigned* __restrict__ part) {
  __shared__ unsigned tk[256 * LSTR];   // lane-private lists (33.8 KB)
  __shared__ unsigned ms[512];          // merge scratch (2 KB)

  const int t = threadIdx.x;
  const int w = t >> 6;
  const int lane = t & 63;
  const int h = lane >> 5;
  const int q = lane & 31;
  const int qblk = (int)(blockIdx.x >> 1);
  const int half = (int)(blockIdx.x & 1);
  const int qg0 = qblk * 32;
  const int t0 = half * 64;
  const int selfq = qg0 + q;
  const float sqq = sq[selfq];
  const int selfTl = qg0 >> 7;            // wave-uniform
  const int selfW = (qg0 >> 5) & 3;       // wave-uniform
  const int selfH = (q >> 2) & 1;
  const int selfR = (q & 3) + 4 * (q >> 3);

  const char* xh = (const char*)xbhi;
  const char* xl = (const char*)xblo;

  bfrag qhi[4], qlo[4];
  {
    const size_t a0 = (size_t)qblk * 4096 + (size_t)lane * 16;
#pragma unroll
    for (int s = 0; s < 4; ++s) {
      qhi[s] = *(const bfrag*)(xh + a0 + s * 1024);
      qlo[s] = *(const bfrag*)(xl + a0 + s * 1024);
    }
  }
  asm volatile("" :: "v"(qhi[0]), "v"(qhi[1]), "v"(qhi[2]), "v"(qhi[3]),
                     "v"(qlo[0]), "v"(qlo[1]), "v"(qlo[2]), "v"(qlo[3]));

  unsigned* mylist = &tk[t * LSTR];
  unsigned mxk = 0xFFFFFFFFu;           // cached max key of list
  int mp = 0;                           // its slot
  float thrF = 1e38f;                   // conservative float gate

#define LOADP(GT, PH, PL) { \
  const size_t bb_ = (size_t)((GT) * 4 + w) * 4096 + (size_t)lane * 16; \
  _Pragma("unroll") for (int s_ = 0; s_ < 4; ++s_) { \
    PH[s_] = *(const bfrag*)(xh + bb_ + s_ * 1024); \
    PL[s_] = *(const bfrag*)(xl + bb_ + s_ * 1024); } }

#define SQLOAD(GT, SQv) { \
  const float* sb_ = sq + (GT) * 128 + w * 32 + 4 * h; \
  const float4 q0_ = *(const float4*)(sb_); \
  const float4 q1_ = *(const float4*)(sb_ + 8); \
  const float4 q2_ = *(const float4*)(sb_ + 16); \
  const float4 q3_ = *(const float4*)(sb_ + 24); \
  SQv[0]=q0_.x; SQv[1]=q0_.y; SQv[2]=q0_.z; SQv[3]=q0_.w; \
  SQv[4]=q1_.x; SQv[5]=q1_.y; SQv[6]=q1_.z; SQv[7]=q1_.w; \
  SQv[8]=q2_.x; SQv[9]=q2_.y; SQv[10]=q2_.z; SQv[11]=q2_.w; \
  SQv[12]=q3_.x; SQv[13]=q3_.y; SQv[14]=q3_.z; SQv[15]=q3_.w; }

#define PIN(PH, PL) asm volatile("" :: "v"(PH[0]), "v"(PH[1]), "v"(PH[2]), "v"(PH[3]), \
                                       "v"(PL[0]), "v"(PL[1]), "v"(PL[2]), "v"(PL[3]));

#define MFMA12(A0, PH, PL) { \
  _Pragma("unroll") for (int s_ = 0; s_ < 4; ++s_) \
    A0 = __builtin_amdgcn_mfma_f32_32x32x16_bf16(PH[s_], qhi[s_], A0, 0, 0, 0); \
  _Pragma("unroll") for (int s_ = 0; s_ < 4; ++s_) \
    A0 = __builtin_amdgcn_mfma_f32_32x32x16_bf16(PH[s_], qlo[s_], A0, 0, 0, 0); \
  _Pragma("unroll") for (int s_ = 0; s_ < 4; ++s_) \
    A0 = __builtin_amdgcn_mfma_f32_32x32x16_bf16(PL[s_], qhi[s_], A0, 0, 0, 0); }

#define DCALC(A0, SQv, GT) { \
  _Pragma("unroll") for (int r_ = 0; r_ < 16; ++r_) \
    A0[r_] = fmaf(-2.0f, A0[r_], sqq + SQv[r_]); \
  if ((GT) == selfTl && w == selfW) { \
    _Pragma("unroll") for (int r_ = 0; r_ < 16; ++r_) \
      if (h == selfH && r_ == selfR) A0[r_] = 1e30f; } }

#define PACKKEY(D2, PIDX, KEY) { \
  unsigned dq_ = (unsigned)((D2) * 256.0f); \
  dq_ = dq_ > 0x3FFEFu ? 0x3FFEFu : dq_; \
  KEY = (dq_ << 14) | (unsigned)(PIDX); }

  // 15-cndmask static select: D = A0[B] (B in 0..15, runtime)
#define SEL16(A0, B, D) { \
  const bool c0_ = (((B) & 1) != 0); \
  float m0_ = c0_ ? A0[1] : A0[0], m1_ = c0_ ? A0[3] : A0[2]; \
  float m2_ = c0_ ? A0[5] : A0[4], m3_ = c0_ ? A0[7] : A0[6]; \
  float m4_ = c0_ ? A0[9] : A0[8], m5_ = c0_ ? A0[11] : A0[10]; \
  float m6_ = c0_ ? A0[13] : A0[12], m7_ = c0_ ? A0[15] : A0[14]; \
  const bool c1_ = (((B) & 2) != 0); \
  m0_ = c1_ ? m1_ : m0_; m2_ = c1_ ? m3_ : m2_; \
  m4_ = c1_ ? m5_ : m4_; m6_ = c1_ ? m7_ : m6_; \
  const bool c2_ = (((B) & 4) != 0); \
  m0_ = c2_ ? m2_ : m0_; m4_ = c2_ ? m6_ : m4_; \
  D = (((B) & 8) != 0) ? m4_ : m0_; }

#define FILT(A0, GT) { \
  const int pb_ = (GT) * 128 + w * 32 + 4 * h; \
  unsigned msk_ = 0u; \
  _Pragma("unroll") for (int r_ = 0; r_ < 16; ++r_) \
    if (A0[r_] < thrF) msk_ |= (1u << r_); \
  while (__any(msk_ != 0u)) { \
    if (msk_) { \
      const int b_ = (int)__builtin_ctz(msk_); \
      msk_ &= msk_ - 1u; \
      float d_; SEL16(A0, b_, d_) \
      unsigned key_; PACKKEY(d_, pb_ + b_ + (b_ & ~3), key_) \
      if (key_ < mxk) { \
        mylist[mp] = key_; \
        unsigned nm_ = 0u; int np_ = 0; \
        _Pragma("unroll") for (int e_ = 0; e_ < 32; ++e_) { \
          const unsigned v_ = mylist[e_]; \
          if (v_ > nm_) { nm_ = v_; np_ = e_; } } \
        mxk = nm_; mp = np_; \
        thrF = (float)((mxk >> 14) + 1) * (1.0f / 256.0f); \
      } } } }

#define STEP(LT, PHc, PLc, PHn, PLn) { \
  const int gT_ = t0 + (LT); \
  if ((LT) + 1 < 64) LOADP(gT_ + 1, PHn, PLn) \
  f32x16 a0_; \
  _Pragma("unroll") for (int i_ = 0; i_ < 16; ++i_) a0_[i_] = 0.f; \
  MFMA12(a0_, PHc, PLc) \
  PIN(PHn, PLn) \
  float sv_[16]; SQLOAD(gT_, sv_) \
  DCALC(a0_, sv_, gT_) \
  FILT(a0_, gT_) }

  bfrag phA[4], plA[4], phB[4], plB[4];

  // ---- bootstrap: tiles t0, t0+1 fill all 32 slots unconditionally ----
  LOADP(t0, phA, plA) PIN(phA, plA)
  {
    f32x16 a0_;
#pragma unroll
    for (int i_ = 0; i_ < 16; ++i_) a0_[i_] = 0.f;
    MFMA12(a0_, phA, plA)
    LOADP(t0 + 1, phB, plB) PIN(phB, plB)
    float sv_[16]; SQLOAD(t0, sv_)
    DCALC(a0_, sv_, t0)
    const int pb0 = t0 * 128 + w * 32 + 4 * h;
#pragma unroll
    for (int r_ = 0; r_ < 16; ++r_) {
      unsigned key_; PACKKEY(a0_[r_], pb0 + r_ + (r_ & ~3), key_)
      mylist[r_] = key_;
    }
  }
  {
    f32x16 a0_;
#pragma unroll
    for (int i_ = 0; i_ < 16; ++i_) a0_[i_] = 0.f;
    MFMA12(a0_, phB, plB)
    LOADP(t0 + 2, phA, plA) PIN(phA, plA)
    float sv_[16]; SQLOAD(t0 + 1, sv_)
    DCALC(a0_, sv_, t0 + 1)
    const int pb1 = (t0 + 1) * 128 + w * 32 + 4 * h;
#pragma unroll
    for (int r_ = 0; r_ < 16; ++r_) {
      unsigned key_; PACKKEY(a0_[r_], pb1 + r_ + (r_ & ~3), key_)
      mylist[16 + r_] = key_;
    }
    unsigned nm_ = 0u; int np_ = 0;
#pragma unroll
    for (int e_ = 0; e_ < 32; ++e_) {
      const unsigned v_ = mylist[e_];
      if (v_ > nm_) { nm_ = v_; np_ = e_; }
    }
    mxk = nm_; mp = np_;
    thrF = (float)((mxk >> 14) + 1) * (1.0f / 256.0f);
  }

  // ---- steady tiles 2..63 ----
  for (int lt = 2; lt < 62; lt += 2) {
    STEP(lt, phA, plA, phB, plB)
    STEP(lt + 1, phB, plB, phA, plA)
  }
  STEP(62, phA, plA, phB, plB)
  STEP(63, phB, plB, phA, plA)

  __syncthreads();

  // ---- in-block merge: 8 lane-lists -> sorted top-32/query -> part ----
#define SORT64(V) { \
  _Pragma("unroll") for (int k_ = 2; k_ <= 64; k_ <<= 1) { \
    _Pragma("unroll") for (int j_ = k_ >> 1; j_ >= 1; j_ >>= 1) { \
      const unsigned o_ = (unsigned)__shfl_xor((int)V, j_); \
      const bool km_ = ((lane & j_) == 0) == ((lane & k_) == 0); \
      V = km_ ? (V < o_ ? V : o_) : (V > o_ ? V : o_); \
    } } }

#define MERGE6(V) { \
  _Pragma("unroll") for (int j_ = 32; j_ >= 1; j_ >>= 1) { \
    const unsigned o_ = (unsigned)__shfl_xor((int)V, j_); \
    const bool km_ = ((lane & j_) == 0); \
    V = km_ ? (V < o_ ? V : o_) : (V > o_ ? V : o_); \
  } }

  unsigned* S = &ms[w * 128];
  for (int s8 = 0; s8 < 8; ++s8) {
    const int qq = w * 8 + s8;
#pragma unroll
    for (int w2 = 0; w2 < 4; ++w2) {
      unsigned v = tk[(w2 * 64 + (lane & 32) + qq) * LSTR + (lane & 31)];
      SORT64(v)
      if (lane < 32) S[w2 * 32 + lane] = v;
    }
    {
      unsigned v = (lane < 32) ? S[0 * 32 + lane] : S[1 * 32 + (63 - lane)];
      MERGE6(v)
      if (lane < 32) S[0 * 32 + lane] = v;
    }
    {
      unsigned v = (lane < 32) ? S[2 * 32 + lane] : S[3 * 32 + (63 - lane)];
      MERGE6(v)
      if (lane < 32) S[2 * 32 + lane] = v;
    }
    {
      unsigned v = (lane < 32) ? S[0 * 32 + lane] : S[2 * 32 + (63 - lane)];
      MERGE6(v)
      if (lane < 32)
        part[(size_t)(qg0 + qq) * 64 + half * 32 + lane] = v;
    }
  }
#undef LOADP
#undef SQLOAD
#undef PIN
#undef MFMA12
#undef DCALC
#undef PACKKEY
#undef SEL16
#undef FILT
#undef STEP
#undef SORT64
#undef MERGE6
}

// ---------------- KNN pass 2: merge two sorted-32 lists + softmax ----------------
__global__ __launch_bounds__(256) void k_merge(const unsigned* __restrict__ part,
    unsigned short* __restrict__ nidx, float* __restrict__ nw) {
  const int t = threadIdx.x;
  const int w = t >> 6;
  const int lane = t & 63;
  const int q = (int)blockIdx.x * 4 + w;
  const int src = (lane < 32) ? lane : (95 - lane);
  unsigned v = part[(size_t)q * 64 + src];
#pragma unroll
  for (int j = 32; j >= 1; j >>= 1) {
    const unsigned o = (unsigned)__shfl_xor((int)v, j);
    const bool mn = ((lane & j) == 0);
    v = mn ? (v < o ? v : o) : (v > o ? v : o);
  }
  const float d = sqrtf((float)(v >> 14) * (1.0f / 256.0f));
  const float dmin = __shfl(d, 0);
  float e = (lane < 32) ? __expf((dmin - d) * 2.0f) : 0.f;
  float s2 = e;
#pragma unroll
  for (int m = 1; m < 64; m <<= 1) s2 += __shfl_xor(s2, m);
  if (lane < 32) {
    nw[(size_t)q * Kk + lane] = e / s2;
    nidx[(size_t)q * Kk + lane] = (unsigned short)(v & 0x3FFFu);
  }
}

// ---------------- one message-pass step, fused: gather+MLP+LN ----------------
#define RB 32
#define US 36

__global__ __launch_bounds__(256) void k_step(const float* __restrict__ x,
    const float* __restrict__ hin, const unsigned short* __restrict__ nidx,
    const float* __restrict__ nw, const float* __restrict__ Wm1,
    const float* __restrict__ bm1, const float* __restrict__ Wm2,
    const float* __restrict__ bm2, const float* __restrict__ g,
    const float* __restrict__ be, float* __restrict__ hout) {
  __shared__ float updT[2 * Hd + Fd][US];  // upd_in transposed: 320 x 36 (46 KB)
  __shared__ float t1T[Hd][US];            // silu(GEMM1) transposed (18 KB)
  const int t = threadIdx.x;
  const int r0 = blockIdx.x * RB;

  { // stage: hidden | agg (gather) | x, all transposed
    const int r = t >> 3, s = t & 7;
    const int i = r0 + r;
    const float* hr = hin + (size_t)i * Hd + (s << 4);
#pragma unroll
    for (int u = 0; u < 4; ++u) {
      float4 v = *(const float4*)(hr + (u << 2));
      const int c = (s << 4) + (u << 2);
      updT[c + 0][r] = v.x; updT[c + 1][r] = v.y;
      updT[c + 2][r] = v.z; updT[c + 3][r] = v.w;
    }
    float a[16];
#pragma unroll
    for (int u = 0; u < 16; ++u) a[u] = 0.f;
    const unsigned short* ir = nidx + i * Kk;
    const float* wr = nw + i * Kk;
    for (int k = 0; k < Kk; ++k) {
      const float wk = wr[k];
      const float* hv = hin + (size_t)ir[k] * Hd + (s << 4);
#pragma unroll
      for (int u = 0; u < 4; ++u) {
        float4 v = *(const float4*)(hv + (u << 2));
        a[(u << 2) + 0] = fmaf(wk, v.x, a[(u << 2) + 0]);
        a[(u << 2) + 1] = fmaf(wk, v.y, a[(u << 2) + 1]);
        a[(u << 2) + 2] = fmaf(wk, v.z, a[(u << 2) + 2]);
        a[(u << 2) + 3] = fmaf(wk, v.w, a[(u << 2) + 3]);
      }
    }
#pragma unroll
    for (int u = 0; u < 16; ++u) updT[Hd + (s << 4) + u][r] = a[u];
    const float* xr = x + (size_t)i * Fd + (s << 3);
    float4 x0 = *(const float4*)(xr);
    float4 x1 = *(const float4*)(xr + 4);
    const int c = 2 * Hd + (s << 3);
    updT[c + 0][r] = x0.x; updT[c + 1][r] = x0.y;
    updT[c + 2][r] = x0.z; updT[c + 3][r] = x0.w;
    updT[c + 4][r] = x1.x; updT[c + 5][r] = x1.y;
    updT[c + 6][r] = x1.z; updT[c + 7][r] = x1.w;
  }
  __syncthreads();

  const int rg = t >> 5, cg = t & 31;
  const int rr = rg << 2, cc = cg << 2;
  { // GEMM1 [32x320]x[320x128] + silu -> t1T
    float acc[4][4] = {};
#pragma unroll 4
    for (int k = 0; k < 2 * Hd + Fd; ++k) {
      float4 uv = *(const float4*)&updT[k][rr];
      float4 wv = *(const float4*)&Wm1[k * Hd + cc];
      FMA16(acc, uv, wv)
    }
    float4 b1 = *(const float4*)&bm1[cc];
    float bb1[4] = {b1.x, b1.y, b1.z, b1.w};
#pragma unroll
    for (int a = 0; a < 4; ++a)
#pragma unroll
      for (int b = 0; b < 4; ++b) {
        const float z = acc[a][b] + bb1[b];
        t1T[cc + b][rr + a] = z / (1.0f + __expf(-z));
      }
  }
  __syncthreads();
  { // GEMM2 [32x128]x[128x128] + residual + LayerNorm
    float acc[4][4] = {};
#pragma unroll 4
    for (int k = 0; k < Hd; ++k) {
      float4 uv = *(const float4*)&t1T[k][rr];
      float4 wv = *(const float4*)&Wm2[k * Hd + cc];
      FMA16(acc, uv, wv)
    }
    float4 b2 = *(const float4*)&bm2[cc];
    float bb2[4] = {b2.x, b2.y, b2.z, b2.w};
    float v[4][4];
#pragma unroll
    for (int b = 0; b < 4; ++b) {
      float4 hres = *(const float4*)&updT[cc + b][rr];  // residual = staged hidden
      v[0][b] = hres.x + acc[0][b] + bb2[b];
      v[1][b] = hres.y + acc[1][b] + bb2[b];
      v[2][b] = hres.z + acc[2][b] + bb2[b];
      v[3][b] = hres.w + acc[3][b] + bb2[b];
    }
    float4 gv = *(const float4*)&g[cc];
    float4 bev = *(const float4*)&be[cc];
    float gg[4] = {gv.x, gv.y, gv.z, gv.w};
    float eb[4] = {bev.x, bev.y, bev.z, bev.w};
#pragma unroll
    for (int a = 0; a < 4; ++a) {
      float sm = v[a][0] + v[a][1] + v[a][2] + v[a][3];
      float s2 = 0.f;
#pragma unroll
      for (int b = 0; b < 4; ++b) s2 = fmaf(v[a][b], v[a][b], s2);
#pragma unroll
      for (int m = 1; m < 32; m <<= 1) {
        sm += __shfl_xor(sm, m);
        s2 += __shfl_xor(s2, m);
      }
      const float mean = sm * (1.0f / 128.0f);
      const float var = fmaxf(s2 * (1.0f / 128.0f) - mean * mean, 0.0f);
      const float rstd = rsqrtf(var + 1e-5f);
      float4 o;
      o.x = (v[a][0] - mean) * rstd * gg[0] + eb[0];
      o.y = (v[a][1] - mean) * rstd * gg[1] + eb[1];
      o.z = (v[a][2] - mean) * rstd * gg[2] + eb[2];
      o.w = (v[a][3] - mean) * rstd * gg[3] + eb[3];
      *(float4*)&hout[(size_t)(r0 + rr + a) * Hd + cc] = o;
    }
  }
}

// ---------------- readout: softplus(silu([h,x]@Wr1+b)@Wr2+b) ----------------
__global__ __launch_bounds__(256) void k_out(const float* __restrict__ x,
    const float* __restrict__ hin, const float* __restrict__ Wr1,
    const float* __restrict__ br1, const float* __restrict__ Wr2,
    const float* __restrict__ br2, float* __restrict__ out) {
  __shared__ float rT[Hd + Fd][US];  // 192 x 36 (27 KB)
  const int t = threadIdx.x;
  const int r0 = blockIdx.x * RB;
  {
    const int r = t >> 3, s = t & 7;
    const int i = r0 + r;
    const float* hr = hin + (size_t)i * Hd + (s << 4);
#pragma unroll
    for (int u = 0; u < 4; ++u) {
      float4 v = *(const float4*)(hr + (u << 2));
      const int c = (s << 4) + (u << 2);
      rT[c + 0][r] = v.x; rT[c + 1][r] = v.y;
      rT[c + 2][r] = v.z; rT[c + 3][r] = v.w;
    }
    const float* xr = x + (size_t)i * Fd + (s << 3);
    float4 x0 = *(const float4*)(xr);
    float4 x1 = *(const float4*)(xr + 4);
    const int c = Hd + (s << 3);
    rT[c + 0][r] = x0.x; rT[c + 1][r] = x0.y;
    rT[c + 2][r] = x0.z; rT[c + 3][r] = x0.w;
    rT[c + 4][r] = x1.x; rT[c + 5][r] = x1.y;
    rT[c + 6][r] = x1.z; rT[c + 7][r] = x1.w;
  }
  __syncthreads();
  const int rg = t >> 5, cg = t & 31;
  const int rr = rg << 2, cc = cg << 2;
  float acc[4][4] = {};
#pragma unroll 4
  for (int k = 0; k < Hd + Fd; ++k) {
    float4 uv = *(const float4*)&rT[k][rr];
    float4 wv = *(const float4*)&Wr1[k * Hd + cc];
    FMA16(acc, uv, wv)
  }
  float4 b1 = *(const float4*)&br1[cc];
  float bb1[4] = {b1.x, b1.y, b1.z, b1.w};
  float4 w2 = *(const float4*)&Wr2[cc];
  float ww[4] = {w2.x, w2.y, w2.z, w2.w};
  float part[4];
#pragma unroll
  for (int a = 0; a < 4; ++a) {
    part[a] = 0.f;
#pragma unroll
    for (int b = 0; b < 4; ++b) {
      const float z = acc[a][b] + bb1[b];
      const float sil = z / (1.0f + __expf(-z));
      part[a] = fmaf(sil, ww[b], part[a]);
    }
  }
#pragma unroll
  for (int m = 1; m < 32; m <<= 1) {
#pragma unroll
    for (int a = 0; a < 4; ++a) part[a] += __shfl_xor(part[a], m);
  }
  if (cg == 0) {
    const float bias = br2[0];
#pragma unroll
    for (int a = 0; a < 4; ++a) {
      const float rv = part[a] + bias;
      out[r0 + rr + a] = fmaxf(rv, 0.0f) + log1pf(__expf(-fabsf(rv)));
    }
  }
}

extern "C" void kernel_launch(void* const* d_in, const int* in_sizes, int n_in,
                              void* d_out, int out_size, void* d_ws, size_t ws_size,
                              hipStream_t stream) {
  const float* x    = (const float*)d_in[0];
  const float* W_in = (const float*)d_in[1];
  const float* b_in = (const float*)d_in[2];
  const float* W_m1 = (const float*)d_in[3];
  const float* b_m1 = (const float*)d_in[4];
  const float* W_m2 = (const float*)d_in[5];
  const float* b_m2 = (const float*)d_in[6];
  const float* ln_g = (const float*)d_in[7];
  const float* ln_b = (const float*)d_in[8];
  const float* W_r1 = (const float*)d_in[9];
  const float* b_r1 = (const float*)d_in[10];
  const float* W_r2 = (const float*)d_in[11];
  const float* b_r2 = (const float*)d_in[12];
  float* out = (float*)d_out;

  char* ws = (char*)d_ws;
  const size_t MB = (size_t)1 << 20;
  float*          hidA = (float*)(ws);                 // 8 MB
  float*          hidB = (float*)(ws + 8 * MB);        // 8 MB (aliases partbuf)
  unsigned*       partb = (unsigned*)(ws + 8 * MB);    // 4 MB, dead before hidB use
  short*          xbhi = (short*)(ws + 16 * MB);       // 2 MB
  short*          xblo = (short*)(ws + 18 * MB);       // 2 MB
  unsigned short* nidx = (unsigned short*)(ws + 20 * MB);  // 1 MB
  float*          nw   = (float*)(ws + 21 * MB);       // 2 MB
  float*          sq   = (float*)(ws + 23 * MB);       // 64 KB

  k_input<<<dim3(Nn / 2), dim3(256), 0, stream>>>(x, W_in, b_in, hidA, sq);
  k_prep<<<dim3(Nn * 8 / 256), dim3(256), 0, stream>>>(x, xbhi, xblo);
  k_knn<<<dim3(Nn / 32 * 2), dim3(256), 0, stream>>>(xbhi, xblo, sq, partb);
  k_merge<<<dim3(Nn / 4), dim3(256), 0, stream>>>(partb, nidx, nw);
  k_step<<<dim3(Nn / RB), dim3(256), 0, stream>>>(x, hidA, nidx, nw, W_m1, b_m1,
                                                  W_m2, b_m2, ln_g, ln_b, hidB);
  k_step<<<dim3(Nn / RB), dim3(256), 0, stream>>>(x, hidB, nidx, nw, W_m1, b_m1,
                                                  W_m2, b_m2, ln_g, ln_b, hidA);
  k_out<<<dim3(Nn / RB), dim3(256), 0, stream>>>(x, hidA, W_r1, b_r1, W_r2, b_r2, out);
}